// Round 6
// baseline (198.453 us; speedup 1.0000x reference)
//
#include <hip/hip_runtime.h>

// Problem: B=4096, S=256, F=64, K=16, L=256
//   logits[b,k,f] = sum_s x[b,s,f] * W[f,s,k]   (x NaN->0)
//   idx[b,f] = argmax_k logits[b,k,f]           (first max wins)
//   out[b,f,l] = snippet_list[f, idx[b,f], l]
constexpr int Bn = 4096, Sn = 256, Fn = 64, Kn = 16;

// W[f][s][k] -> Wl[s][kq][f][r]  (float4 view: Wl4[(s*4+kq)*64+f])
// 262,144 floats = 1 MB.
__global__ void transpose_w_kernel(const float* __restrict__ W, float* __restrict__ Wl) {
  int t = blockIdx.x * 256 + threadIdx.x;          // t = ((s*4+kq)*64+f)*4+r
  int r = t & 3, f = (t >> 2) & 63, kq = (t >> 8) & 3, s = t >> 10;
  Wl[t] = W[(f * Sn + s) * Kn + kq * 4 + r];
}

// GEMM+argmax. Grid 256 blocks x 256 threads (4 waves). Wave w owns batches
// b0 = blk*16 + w*4 + {0..3} over full s. lane = f.
// W staged per 8-s chunk (2048 float4 = 32 KB) in double-buffered LDS shared
// by all 4 waves; W global loads issued BEFORE x loads each chunk so the
// in-order vmcnt retirement never makes a W wait drain the x stream.
__global__ __launch_bounds__(256, 1) void gemm_argmax_kernel(
    const float* __restrict__ x, const float4* __restrict__ Wl4,
    int* __restrict__ idxg) {
  __shared__ float4 buf[2][2048];   // 64 KB: [parity][(s8*4+kq)*64 + f]

  const int tid = threadIdx.x;
  const int lane = tid & 63;            // f
  const int w = tid >> 6;
  const int b0 = blockIdx.x * 16 + w * 4;
  const size_t xrow = (size_t)Sn * Fn;
  const float* xb0 = x + (size_t)b0 * xrow + lane;
  const int slot0 = w * 64 + lane;      // staging slot stride-256 base

  float acc[4][16];
#pragma unroll
  for (int j = 0; j < 4; ++j)
#pragma unroll
    for (int k = 0; k < 16; ++k) acc[j][k] = 0.f;

  float xn[8][4], xc[8][4];
  float4 wst[8];

  // prologue: load W chunk 0 + x chunk 0; write W chunk 0 to buf[0]
#pragma unroll
  for (int i = 0; i < 8; ++i) wst[i] = Wl4[i * 256 + slot0];
#pragma unroll
  for (int s8 = 0; s8 < 8; ++s8)
#pragma unroll
    for (int j = 0; j < 4; ++j) xn[s8][j] = xb0[(size_t)j * xrow + s8 * 64];
#pragma unroll
  for (int i = 0; i < 8; ++i) buf[0][i * 256 + slot0] = wst[i];
  __syncthreads();

  int p = 0;
  for (int c = 0; c < 32; ++c) {
    // commit x chunk c with NaN->0 fix
#pragma unroll
    for (int s8 = 0; s8 < 8; ++s8)
#pragma unroll
      for (int j = 0; j < 4; ++j) {
        float v = xn[s8][j];
        xc[s8][j] = (v == v) ? v : 0.f;
      }
    // issue next chunk's loads: W FIRST, then x (in-order vmcnt discipline)
    if (c < 31) {
#pragma unroll
      for (int i = 0; i < 8; ++i) wst[i] = Wl4[(c + 1) * 2048 + i * 256 + slot0];
#pragma unroll
      for (int s8 = 0; s8 < 8; ++s8)
#pragma unroll
        for (int j = 0; j < 4; ++j)
          xn[s8][j] = xb0[(size_t)j * xrow + (c + 1) * 512 + s8 * 64];
    }
    // compute chunk c from buf[p]
#pragma unroll
    for (int s8 = 0; s8 < 8; ++s8) {
      float4 wq[4];
#pragma unroll
      for (int kq = 0; kq < 4; ++kq) wq[kq] = buf[p][(s8 * 4 + kq) * 64 + lane];
      float wv[16];
#pragma unroll
      for (int kq = 0; kq < 4; ++kq) {
        wv[4 * kq + 0] = wq[kq].x; wv[4 * kq + 1] = wq[kq].y;
        wv[4 * kq + 2] = wq[kq].z; wv[4 * kq + 3] = wq[kq].w;
      }
#pragma unroll
      for (int j = 0; j < 4; ++j)
#pragma unroll
        for (int k = 0; k < 16; ++k)
          acc[j][k] = fmaf(xc[s8][j], wv[k], acc[j][k]);
    }
    // park staged W chunk c+1 into the other buffer (readers use buf[p])
    if (c < 31) {
#pragma unroll
      for (int i = 0; i < 8; ++i) buf[p ^ 1][i * 256 + slot0] = wst[i];
    }
    __syncthreads();
    p ^= 1;
  }

  // per-thread argmax (strict >, ascending k: first max wins) + idx store
#pragma unroll
  for (int j = 0; j < 4; ++j) {
    float bv = acc[j][0];
    int bk = 0;
#pragma unroll
    for (int k = 1; k < 16; ++k)
      if (acc[j][k] > bv) { bv = acc[j][k]; bk = k; }
    idxg[(b0 + j) * 64 + lane] = bk;
  }
}

// Pure streaming gather: row r = b*64+f (262,144 rows of 1 KB).
// 4096 blocks x 256 thr = 16,384 waves, 16 rows each.
__global__ __launch_bounds__(256) void gather_kernel(
    const int* __restrict__ idxg, const float4* __restrict__ snip4,
    float4* __restrict__ out4) {
  const int lane = threadIdx.x & 63;
  const int gw = (blockIdx.x * 256 + threadIdx.x) >> 6;
  const int r0 = gw * 16;
  int kk[16];
#pragma unroll
  for (int i = 0; i < 16; ++i) kk[i] = idxg[r0 + i];
#pragma unroll
  for (int i = 0; i < 16; ++i) {
    const int r = r0 + i;
    const int f = r & 63;
    out4[(size_t)r * 64 + lane] = snip4[(size_t)((f * Kn + kk[i]) * 64) + lane];
  }
}

// Fallback (ws too small): R5's verified fused kernel, direct W reads.
__global__ __launch_bounds__(256, 2) void fused_fallback(
    const float* __restrict__ x, const float* __restrict__ Wsrc,
    const float4* __restrict__ snip4, float4* __restrict__ out4) {
  __shared__ int idxs[8][64];
  const int tid = threadIdx.x;
  const int lane = tid & 63;
  const int w = tid >> 6;
  const int bbase = blockIdx.x * 8;
  const int b0 = bbase + w * 2;
  const size_t xrow = (size_t)Sn * Fn;

  float acc0[16], acc1[16];
#pragma unroll
  for (int k = 0; k < 16; ++k) { acc0[k] = 0.f; acc1[k] = 0.f; }
  const float* pc0 = x + (size_t)b0 * xrow + lane;
  const float* pc1 = pc0 + xrow;
  float xc0[8], xc1[8], xn0[8], xn1[8];
#pragma unroll
  for (int j = 0; j < 8; ++j) { xn0[j] = pc0[j * 64]; xn1[j] = pc1[j * 64]; }
  for (int c = 0; c < 32; ++c) {
#pragma unroll
    for (int j = 0; j < 8; ++j) {
      float v0 = xn0[j], v1 = xn1[j];
      xc0[j] = (v0 == v0) ? v0 : 0.f;
      xc1[j] = (v1 == v1) ? v1 : 0.f;
    }
    if (c < 31) {
      pc0 += 512; pc1 += 512;
#pragma unroll
      for (int j = 0; j < 8; ++j) { xn0[j] = pc0[j * 64]; xn1[j] = pc1[j * 64]; }
    }
#pragma unroll
    for (int s8 = 0; s8 < 8; ++s8) {
      const int s = c * 8 + s8;
      float wv[16];
      const float4* wq = reinterpret_cast<const float4*>(Wsrc) + ((size_t)(lane * Sn + s) << 2);
#pragma unroll
      for (int jj = 0; jj < 4; ++jj) {
        float4 q = wq[jj];
        wv[4 * jj + 0] = q.x; wv[4 * jj + 1] = q.y; wv[4 * jj + 2] = q.z; wv[4 * jj + 3] = q.w;
      }
#pragma unroll
      for (int k = 0; k < 16; ++k) {
        acc0[k] = fmaf(xc0[s8], wv[k], acc0[k]);
        acc1[k] = fmaf(xc1[s8], wv[k], acc1[k]);
      }
    }
  }
  {
    float bv0 = acc0[0], bv1 = acc1[0];
    int bk0 = 0, bk1 = 0;
#pragma unroll
    for (int k = 1; k < 16; ++k) {
      if (acc0[k] > bv0) { bv0 = acc0[k]; bk0 = k; }
      if (acc1[k] > bv1) { bv1 = acc1[k]; bk1 = k; }
    }
    idxs[w * 2 + 0][lane] = bk0;
    idxs[w * 2 + 1][lane] = bk1;
  }
  __syncthreads();
#pragma unroll 4
  for (int it = 0; it < 128; ++it) {
    int r = (it << 2) | w;
    int bi = r >> 6, f = r & 63;
    int kk = idxs[bi][f];
    float4 v = snip4[(size_t)((f * Kn + kk) << 6) + lane];
    out4[((size_t)(bbase + bi) * Fn + f) * 64 + lane] = v;
  }
}

extern "C" void kernel_launch(void* const* d_in, const int* in_sizes, int n_in,
                              void* d_out, int out_size, void* d_ws, size_t ws_size,
                              hipStream_t stream) {
  const float* x = (const float*)d_in[0];
  const float* W = (const float*)d_in[1];
  const float* snip = (const float*)d_in[2];
  float4* out4 = (float4*)d_out;
  const float4* snip4 = (const float4*)snip;

  const size_t wl_bytes = (size_t)Sn * Fn * Kn * sizeof(float);   // 1 MB
  const size_t idx_bytes = (size_t)Bn * Fn * sizeof(int);         // 1 MB
  if (ws_size >= wl_bytes + idx_bytes) {
    float* Wl = (float*)d_ws;
    int* idxg = (int*)((char*)d_ws + wl_bytes);
    transpose_w_kernel<<<(Sn * Fn * Kn) / 256, 256, 0, stream>>>(W, Wl);
    gemm_argmax_kernel<<<Bn / 16, 256, 0, stream>>>(x, (const float4*)Wl, idxg);
    gather_kernel<<<(Bn * Fn) / (4 * 16), 256, 0, stream>>>(idxg, snip4, out4);
  } else {
    fused_fallback<<<Bn / 8, 256, 0, stream>>>(x, W, snip4, out4);
  }
}